// Round 1
// baseline (1495.414 us; speedup 1.0000x reference)
//
#include <hip/hip_runtime.h>
#include <math.h>

#define N_NODES 100000
#define N_EDGES 1600000
#define D 128
#define SCAN_CHUNK 1024
#define N_SCAN_BLOCKS 98   // ceil(100000/1024)

// ---------------- CSR build ----------------

__global__ __launch_bounds__(256) void k_count(const int* __restrict__ dst,
                                               int* __restrict__ counts) {
  int e = blockIdx.x * 256 + threadIdx.x;
  if (e < N_EDGES) atomicAdd(&counts[dst[e]], 1);
}

__global__ __launch_bounds__(256) void k_scan1(const int* __restrict__ counts,
                                               int* __restrict__ bsum) {
  __shared__ int red[256];
  int base = blockIdx.x * SCAN_CHUNK + threadIdx.x * 4;
  int s = 0;
#pragma unroll
  for (int j = 0; j < 4; j++) {
    int i = base + j;
    s += (i < N_NODES) ? counts[i] : 0;
  }
  red[threadIdx.x] = s;
  __syncthreads();
  for (int off = 128; off > 0; off >>= 1) {
    if (threadIdx.x < off) red[threadIdx.x] += red[threadIdx.x + off];
    __syncthreads();
  }
  if (threadIdx.x == 0) bsum[blockIdx.x] = red[0];
}

__global__ void k_scan2(const int* __restrict__ bsum, int* __restrict__ boff,
                        int* __restrict__ row_ptr, int nb) {
  if (threadIdx.x == 0) {
    int run = 0;
    for (int i = 0; i < nb; i++) { boff[i] = run; run += bsum[i]; }
    row_ptr[N_NODES] = run;   // == N_EDGES
  }
}

__global__ __launch_bounds__(256) void k_scan3(const int* __restrict__ counts,
                                               const int* __restrict__ boff,
                                               int* __restrict__ row_ptr,
                                               int* __restrict__ cursor,
                                               float* __restrict__ inv_deg) {
  __shared__ int sd[256];
  int base = blockIdx.x * SCAN_CHUNK + threadIdx.x * 4;
  int c[4];
  int s = 0;
#pragma unroll
  for (int j = 0; j < 4; j++) {
    int i = base + j;
    c[j] = (i < N_NODES) ? counts[i] : 0;
    s += c[j];
  }
  sd[threadIdx.x] = s;
  __syncthreads();
  // inclusive Hillis-Steele scan over 256 thread sums
  for (int off = 1; off < 256; off <<= 1) {
    int add = (threadIdx.x >= off) ? sd[threadIdx.x - off] : 0;
    __syncthreads();
    sd[threadIdx.x] += add;
    __syncthreads();
  }
  int excl = (threadIdx.x ? sd[threadIdx.x - 1] : 0) + boff[blockIdx.x];
#pragma unroll
  for (int j = 0; j < 4; j++) {
    int i = base + j;
    if (i < N_NODES) {
      row_ptr[i] = excl;
      cursor[i] = excl;
      inv_deg[i] = 1.0f / fmaxf((float)c[j], 1.0f);
      excl += c[j];
    }
  }
}

__global__ __launch_bounds__(256) void k_scatter(const int* __restrict__ src,
                                                 const int* __restrict__ dst,
                                                 int* __restrict__ cursor,
                                                 int* __restrict__ ssrc) {
  int e = blockIdx.x * 256 + threadIdx.x;
  if (e < N_EDGES) {
    int pos = atomicAdd(&cursor[dst[e]], 1);
    ssrc[pos] = src[e];
  }
}

// ---------------- GIN aggregation: z = (1+eps)*h + mean_{j in N(i)} h_j ----------------
// 256 threads = 2 nodes/block, thread handles one feature dim of one node.
__global__ __launch_bounds__(256) void k_agg(const float* __restrict__ h,
                                             float* __restrict__ z,
                                             const int* __restrict__ row_ptr,
                                             const int* __restrict__ ssrc,
                                             const float* __restrict__ inv_deg,
                                             const float* __restrict__ eps,
                                             int layer) {
  int node = blockIdx.x * 2 + (threadIdx.x >> 7);
  int d = threadIdx.x & 127;
  int beg = row_ptr[node];
  int end = row_ptr[node + 1];
  float s = 0.f;
  for (int e = beg; e < end; ++e) {
    int sn = ssrc[e];
    s += h[(size_t)sn * D + d];
  }
  float ep1 = 1.0f + eps[layer];
  z[(size_t)node * D + d] = ep1 * h[(size_t)node * D + d] + s * inv_deg[node];
}

// ---------------- f32 GEMM: C = leaky_relu(A[nrows,128] @ W[128,128] + b) ----------------
// block: 256 threads, 128 rows x 128 cols, 8x8 per thread, K-step 8.
__global__ __launch_bounds__(256) void k_gemm(const float* __restrict__ A,
                                              const float* __restrict__ W,
                                              const float* __restrict__ bias,
                                              float* __restrict__ C, int nrows) {
  __shared__ float As[8][128];  // [kk][row] (transposed tile)
  __shared__ float Ws[8][128];  // [kk][col]
  const int tid = threadIdx.x;
  const int row0 = blockIdx.x * 128;
  const int tr = tid >> 4;  // 0..15 -> rows tr*8 .. tr*8+7
  const int tc = tid & 15;  // 0..15 -> cols {tc*4..+3, 64+tc*4..+3}

  float acc[8][8];
#pragma unroll
  for (int i = 0; i < 8; i++)
#pragma unroll
    for (int j = 0; j < 8; j++) acc[i][j] = 0.f;

  // staging indices
  const int ar = tid >> 1;        // 0..127 row
  const int ak = (tid & 1) * 4;   // 0 or 4
  int arow = row0 + ar;
  if (arow >= nrows) arow = nrows - 1;  // clamp (results discarded on store)
  const int wk = tid >> 5;        // 0..7
  const int wc = (tid & 31) * 4;  // 0..124

  for (int k0 = 0; k0 < 128; k0 += 8) {
    float4 av = *(const float4*)(A + (size_t)arow * D + k0 + ak);
    float4 wv = *(const float4*)(W + (size_t)(k0 + wk) * D + wc);
    As[ak + 0][ar] = av.x;
    As[ak + 1][ar] = av.y;
    As[ak + 2][ar] = av.z;
    As[ak + 3][ar] = av.w;
    *(float4*)&Ws[wk][wc] = wv;
    __syncthreads();
#pragma unroll
    for (int kk = 0; kk < 8; kk++) {
      float4 a0 = *(const float4*)&As[kk][tr * 8];
      float4 a1 = *(const float4*)&As[kk][tr * 8 + 4];
      float4 w0 = *(const float4*)&Ws[kk][tc * 4];
      float4 w1 = *(const float4*)&Ws[kk][tc * 4 + 64];
      float a[8] = {a0.x, a0.y, a0.z, a0.w, a1.x, a1.y, a1.z, a1.w};
      float w[8] = {w0.x, w0.y, w0.z, w0.w, w1.x, w1.y, w1.z, w1.w};
#pragma unroll
      for (int i = 0; i < 8; i++)
#pragma unroll
        for (int j = 0; j < 8; j++) acc[i][j] += a[i] * w[j];
    }
    __syncthreads();
  }

#pragma unroll
  for (int i = 0; i < 8; i++) {
    int r = row0 + tr * 8 + i;
    if (r < nrows) {
#pragma unroll
      for (int half = 0; half < 2; half++) {
        int cbase = half * 64 + tc * 4;
        float4 o;
        float v0 = acc[i][half * 4 + 0] + bias[cbase + 0];
        float v1 = acc[i][half * 4 + 1] + bias[cbase + 1];
        float v2 = acc[i][half * 4 + 2] + bias[cbase + 2];
        float v3 = acc[i][half * 4 + 3] + bias[cbase + 3];
        o.x = v0 > 0.f ? v0 : 0.01f * v0;
        o.y = v1 > 0.f ? v1 : 0.01f * v1;
        o.z = v2 > 0.f ? v2 : 0.01f * v2;
        o.w = v3 > 0.f ? v3 : 0.01f * v3;
        *(float4*)(C + (size_t)r * D + cbase) = o;
      }
    }
  }
}

// ---------------- output head: n_out = h @ Wout[128,2] + bout ----------------
__global__ __launch_bounds__(256) void k_out(const float* __restrict__ h,
                                             const float* __restrict__ Wout,
                                             const float* __restrict__ bout,
                                             float* __restrict__ out) {
  int node = blockIdx.x * 4 + (threadIdx.x >> 6);
  int lane = threadIdx.x & 63;
  float2 hv = *(const float2*)(h + (size_t)node * D + lane * 2);
  float4 wv = *(const float4*)(Wout + lane * 4);  // Wout[2l][0..1], Wout[2l+1][0..1]
  float p0 = hv.x * wv.x + hv.y * wv.z;
  float p1 = hv.x * wv.y + hv.y * wv.w;
#pragma unroll
  for (int off = 32; off > 0; off >>= 1) {
    p0 += __shfl_down(p0, off, 64);
    p1 += __shfl_down(p1, off, 64);
  }
  if (lane == 0) {
    out[node * 2 + 0] = p0 + bout[0];
    out[node * 2 + 1] = p1 + bout[1];
  }
}

// ---------------- launch ----------------

extern "C" void kernel_launch(void* const* d_in, const int* in_sizes, int n_in,
                              void* d_out, int out_size, void* d_ws, size_t ws_size,
                              hipStream_t stream) {
  const float* x = (const float*)d_in[0];
  const int* src = (const int*)d_in[1];
  const int* dst = (const int*)d_in[2];
  const float* W1 = (const float*)d_in[3];
  const float* b1 = (const float*)d_in[4];
  const float* W2 = (const float*)d_in[5];
  const float* b2 = (const float*)d_in[6];
  const float* eps = (const float*)d_in[7];
  const float* Wout = (const float*)d_in[8];
  const float* bout = (const float*)d_in[9];
  float* out = (float*)d_out;
  float* n_embed = out + (size_t)2 * N_NODES;  // [100000,128] region of d_out

  char* ws = (char*)d_ws;
  size_t off = 0;
  auto alloc = [&](size_t bytes) -> char* {
    char* p = ws + off;
    off += (bytes + 511) & ~(size_t)511;
    return p;
  };
  float* bufA = (float*)alloc(sizeof(float) * (size_t)N_NODES * D);  // 51.2 MB
  int* counts = (int*)alloc(sizeof(int) * N_NODES);
  int* row_ptr = (int*)alloc(sizeof(int) * (N_NODES + 1));
  int* cursor = (int*)alloc(sizeof(int) * N_NODES);
  float* inv_deg = (float*)alloc(sizeof(float) * N_NODES);
  int* bsum = (int*)alloc(sizeof(int) * 128);
  int* boff = (int*)alloc(sizeof(int) * 128);
  int* ssrc = (int*)alloc(sizeof(int) * N_EDGES);  // 6.4 MB

  // CSR build (counting sort by dst)
  hipMemsetAsync(counts, 0, sizeof(int) * N_NODES, stream);
  k_count<<<N_EDGES / 256, 256, 0, stream>>>(dst, counts);
  k_scan1<<<N_SCAN_BLOCKS, 256, 0, stream>>>(counts, bsum);
  k_scan2<<<1, 64, 0, stream>>>(bsum, boff, row_ptr, N_SCAN_BLOCKS);
  k_scan3<<<N_SCAN_BLOCKS, 256, 0, stream>>>(counts, boff, row_ptr, cursor, inv_deg);
  k_scatter<<<N_EDGES / 256, 256, 0, stream>>>(src, dst, cursor, ssrc);

  // 3 GIN layers, ping-pong between bufA (t0) and n_embed (t1)
  const float* hin = x;
  float* t0 = bufA;
  float* t1 = n_embed;
  for (int l = 0; l < 3; l++) {
    float* za = (l % 2 == 0) ? t1 : t0;
    float* zb = (l % 2 == 0) ? t0 : t1;
    k_agg<<<N_NODES / 2, 256, 0, stream>>>(hin, za, row_ptr, ssrc, inv_deg, eps, l);
    k_gemm<<<(N_NODES + 127) / 128, 256, 0, stream>>>(za, W1 + (size_t)l * D * D,
                                                      b1 + (size_t)l * D, zb, N_NODES);
    k_gemm<<<(N_NODES + 127) / 128, 256, 0, stream>>>(zb, W2 + (size_t)l * D * D,
                                                      b2 + (size_t)l * D, za, N_NODES);
    hin = za;
  }
  // hin == n_embed here (already in place in d_out)
  k_out<<<N_NODES / 4, 256, 0, stream>>>(n_embed, Wout, bout, out);
}

// Round 2
// 1005.856 us; speedup vs baseline: 1.4867x; 1.4867x over previous
//
#include <hip/hip_runtime.h>
#include <math.h>

#define N_NODES 100000
#define N_EDGES 1600000
#define D 128
#define SCAN_CHUNK 1024
#define N_SCAN_BLOCKS 98   // ceil(100000/1024)

// ---------------- CSR build ----------------

__global__ __launch_bounds__(256) void k_count(const int* __restrict__ dst,
                                               int* __restrict__ counts) {
  int e = blockIdx.x * 256 + threadIdx.x;
  if (e < N_EDGES) atomicAdd(&counts[dst[e]], 1);
}

__global__ __launch_bounds__(256) void k_scan1(const int* __restrict__ counts,
                                               int* __restrict__ bsum) {
  __shared__ int red[256];
  int base = blockIdx.x * SCAN_CHUNK + threadIdx.x * 4;
  int s = 0;
#pragma unroll
  for (int j = 0; j < 4; j++) {
    int i = base + j;
    s += (i < N_NODES) ? counts[i] : 0;
  }
  red[threadIdx.x] = s;
  __syncthreads();
  for (int off = 128; off > 0; off >>= 1) {
    if (threadIdx.x < off) red[threadIdx.x] += red[threadIdx.x + off];
    __syncthreads();
  }
  if (threadIdx.x == 0) bsum[blockIdx.x] = red[0];
}

__global__ void k_scan2(const int* __restrict__ bsum, int* __restrict__ boff,
                        int* __restrict__ row_ptr, int nb) {
  if (threadIdx.x == 0) {
    int run = 0;
    for (int i = 0; i < nb; i++) { boff[i] = run; run += bsum[i]; }
    row_ptr[N_NODES] = run;   // == N_EDGES
  }
}

__global__ __launch_bounds__(256) void k_scan3(const int* __restrict__ counts,
                                               const int* __restrict__ boff,
                                               int* __restrict__ row_ptr,
                                               int* __restrict__ cursor,
                                               float* __restrict__ inv_deg) {
  __shared__ int sd[256];
  int base = blockIdx.x * SCAN_CHUNK + threadIdx.x * 4;
  int c[4];
  int s = 0;
#pragma unroll
  for (int j = 0; j < 4; j++) {
    int i = base + j;
    c[j] = (i < N_NODES) ? counts[i] : 0;
    s += c[j];
  }
  sd[threadIdx.x] = s;
  __syncthreads();
  // inclusive Hillis-Steele scan over 256 thread sums
  for (int off = 1; off < 256; off <<= 1) {
    int add = (threadIdx.x >= off) ? sd[threadIdx.x - off] : 0;
    __syncthreads();
    sd[threadIdx.x] += add;
    __syncthreads();
  }
  int excl = (threadIdx.x ? sd[threadIdx.x - 1] : 0) + boff[blockIdx.x];
#pragma unroll
  for (int j = 0; j < 4; j++) {
    int i = base + j;
    if (i < N_NODES) {
      row_ptr[i] = excl;
      cursor[i] = excl;
      inv_deg[i] = 1.0f / fmaxf((float)c[j], 1.0f);
      excl += c[j];
    }
  }
}

__global__ __launch_bounds__(256) void k_scatter(const int* __restrict__ src,
                                                 const int* __restrict__ dst,
                                                 int* __restrict__ cursor,
                                                 int* __restrict__ ssrc) {
  int e = blockIdx.x * 256 + threadIdx.x;
  if (e < N_EDGES) {
    int pos = atomicAdd(&cursor[dst[e]], 1);
    ssrc[pos] = src[e];
  }
}

// ---------------- GIN aggregation: z = (1+eps)*h + mean_{j in N(i)} h_j ----------------
// One wave per node. Lane t owns dims {2t, 2t+1} (float2, 8B -> wave covers the
// full 512B row in one vmem instruction). 4-edge manual unroll => 4 independent
// gathers in flight per thread (the R1 version had 1x4B: latency-bound, VALUBusy 14%).
__global__ __launch_bounds__(256) void k_agg(const float* __restrict__ h,
                                             float* __restrict__ z,
                                             const int* __restrict__ row_ptr,
                                             const int* __restrict__ ssrc,
                                             const float* __restrict__ inv_deg,
                                             const float* __restrict__ eps,
                                             int layer) {
  int node = blockIdx.x * 4 + (threadIdx.x >> 6);
  int t = threadIdx.x & 63;
  int beg = row_ptr[node];
  int end = row_ptr[node + 1];
  const float* hp = h + 2 * t;
  float ax0 = 0.f, ay0 = 0.f, ax1 = 0.f, ay1 = 0.f;
  float ax2 = 0.f, ay2 = 0.f, ax3 = 0.f, ay3 = 0.f;
  int e = beg;
  for (; e + 4 <= end; e += 4) {
    int i0 = ssrc[e + 0];
    int i1 = ssrc[e + 1];
    int i2 = ssrc[e + 2];
    int i3 = ssrc[e + 3];
    float2 v0 = *(const float2*)(hp + (size_t)i0 * D);
    float2 v1 = *(const float2*)(hp + (size_t)i1 * D);
    float2 v2 = *(const float2*)(hp + (size_t)i2 * D);
    float2 v3 = *(const float2*)(hp + (size_t)i3 * D);
    ax0 += v0.x; ay0 += v0.y;
    ax1 += v1.x; ay1 += v1.y;
    ax2 += v2.x; ay2 += v2.y;
    ax3 += v3.x; ay3 += v3.y;
  }
  for (; e < end; ++e) {
    int i = ssrc[e];
    float2 v = *(const float2*)(hp + (size_t)i * D);
    ax0 += v.x; ay0 += v.y;
  }
  float sx = (ax0 + ax1) + (ax2 + ax3);
  float sy = (ay0 + ay1) + (ay2 + ay3);
  float2 hv = *(const float2*)(hp + (size_t)node * D);
  float ep1 = 1.0f + eps[layer];
  float id = inv_deg[node];
  float2 o;
  o.x = ep1 * hv.x + sx * id;
  o.y = ep1 * hv.y + sy * id;
  *(float2*)(z + (size_t)node * D + 2 * t) = o;
}

// ---------------- f32 GEMM: C = leaky_relu(A[nrows,128] @ W[128,128] + b) ----------------
// block: 256 threads, 128 rows x 128 cols, 8x8 per thread, K-step 32 (8 barriers total).
__global__ __launch_bounds__(256) void k_gemm(const float* __restrict__ A,
                                              const float* __restrict__ W,
                                              const float* __restrict__ bias,
                                              float* __restrict__ C, int nrows) {
  __shared__ float As[32][128];  // [kk][row] (transposed tile), 16 KB
  __shared__ float Ws[32][128];  // [kk][col], 16 KB
  const int tid = threadIdx.x;
  const int row0 = blockIdx.x * 128;
  const int tr = tid >> 4;  // 0..15 -> rows tr*8 .. tr*8+7
  const int tc = tid & 15;  // 0..15 -> cols {tc*4..+3, 64+tc*4..+3}

  float acc[8][8];
#pragma unroll
  for (int i = 0; i < 8; i++)
#pragma unroll
    for (int j = 0; j < 8; j++) acc[i][j] = 0.f;

  // staging indices: A tile 128x32 = 1024 float4s = 4/thread; same for W.
  const int ar = tid >> 1;        // 0..127 row
  const int ak = (tid & 1) * 4;   // 0 or 4
  int arow = row0 + ar;
  if (arow >= nrows) arow = nrows - 1;  // clamp (results discarded on store)
  const int wk = tid >> 5;        // 0..7
  const int wc = (tid & 31) * 4;  // 0..124
  const float* Arow = A + (size_t)arow * D;

  for (int k0 = 0; k0 < 128; k0 += 32) {
#pragma unroll
    for (int j = 0; j < 4; j++) {
      float4 av = *(const float4*)(Arow + k0 + ak + 8 * j);
      As[ak + 8 * j + 0][ar] = av.x;
      As[ak + 8 * j + 1][ar] = av.y;
      As[ak + 8 * j + 2][ar] = av.z;
      As[ak + 8 * j + 3][ar] = av.w;
    }
#pragma unroll
    for (int j = 0; j < 4; j++) {
      float4 wv = *(const float4*)(W + (size_t)(k0 + wk + 8 * j) * D + wc);
      *(float4*)&Ws[wk + 8 * j][wc] = wv;
    }
    __syncthreads();
#pragma unroll 8
    for (int kk = 0; kk < 32; kk++) {
      float4 a0 = *(const float4*)&As[kk][tr * 8];
      float4 a1 = *(const float4*)&As[kk][tr * 8 + 4];
      float4 w0 = *(const float4*)&Ws[kk][tc * 4];
      float4 w1 = *(const float4*)&Ws[kk][tc * 4 + 64];
      float a[8] = {a0.x, a0.y, a0.z, a0.w, a1.x, a1.y, a1.z, a1.w};
      float w[8] = {w0.x, w0.y, w0.z, w0.w, w1.x, w1.y, w1.z, w1.w};
#pragma unroll
      for (int i = 0; i < 8; i++)
#pragma unroll
        for (int j = 0; j < 8; j++) acc[i][j] += a[i] * w[j];
    }
    __syncthreads();
  }

#pragma unroll
  for (int i = 0; i < 8; i++) {
    int r = row0 + tr * 8 + i;
    if (r < nrows) {
#pragma unroll
      for (int half = 0; half < 2; half++) {
        int cbase = half * 64 + tc * 4;
        float4 o;
        float v0 = acc[i][half * 4 + 0] + bias[cbase + 0];
        float v1 = acc[i][half * 4 + 1] + bias[cbase + 1];
        float v2 = acc[i][half * 4 + 2] + bias[cbase + 2];
        float v3 = acc[i][half * 4 + 3] + bias[cbase + 3];
        o.x = v0 > 0.f ? v0 : 0.01f * v0;
        o.y = v1 > 0.f ? v1 : 0.01f * v1;
        o.z = v2 > 0.f ? v2 : 0.01f * v2;
        o.w = v3 > 0.f ? v3 : 0.01f * v3;
        *(float4*)(C + (size_t)r * D + cbase) = o;
      }
    }
  }
}

// ---------------- output head: n_out = h @ Wout[128,2] + bout ----------------
__global__ __launch_bounds__(256) void k_out(const float* __restrict__ h,
                                             const float* __restrict__ Wout,
                                             const float* __restrict__ bout,
                                             float* __restrict__ out) {
  int node = blockIdx.x * 4 + (threadIdx.x >> 6);
  int lane = threadIdx.x & 63;
  float2 hv = *(const float2*)(h + (size_t)node * D + lane * 2);
  float4 wv = *(const float4*)(Wout + lane * 4);  // Wout[2l][0..1], Wout[2l+1][0..1]
  float p0 = hv.x * wv.x + hv.y * wv.z;
  float p1 = hv.x * wv.y + hv.y * wv.w;
#pragma unroll
  for (int off = 32; off > 0; off >>= 1) {
    p0 += __shfl_down(p0, off, 64);
    p1 += __shfl_down(p1, off, 64);
  }
  if (lane == 0) {
    out[node * 2 + 0] = p0 + bout[0];
    out[node * 2 + 1] = p1 + bout[1];
  }
}

// ---------------- launch ----------------

extern "C" void kernel_launch(void* const* d_in, const int* in_sizes, int n_in,
                              void* d_out, int out_size, void* d_ws, size_t ws_size,
                              hipStream_t stream) {
  const float* x = (const float*)d_in[0];
  const int* src = (const int*)d_in[1];
  const int* dst = (const int*)d_in[2];
  const float* W1 = (const float*)d_in[3];
  const float* b1 = (const float*)d_in[4];
  const float* W2 = (const float*)d_in[5];
  const float* b2 = (const float*)d_in[6];
  const float* eps = (const float*)d_in[7];
  const float* Wout = (const float*)d_in[8];
  const float* bout = (const float*)d_in[9];
  float* out = (float*)d_out;
  float* n_embed = out + (size_t)2 * N_NODES;  // [100000,128] region of d_out

  char* ws = (char*)d_ws;
  size_t off = 0;
  auto alloc = [&](size_t bytes) -> char* {
    char* p = ws + off;
    off += (bytes + 511) & ~(size_t)511;
    return p;
  };
  float* bufA = (float*)alloc(sizeof(float) * (size_t)N_NODES * D);  // 51.2 MB
  int* counts = (int*)alloc(sizeof(int) * N_NODES);
  int* row_ptr = (int*)alloc(sizeof(int) * (N_NODES + 1));
  int* cursor = (int*)alloc(sizeof(int) * N_NODES);
  float* inv_deg = (float*)alloc(sizeof(float) * N_NODES);
  int* bsum = (int*)alloc(sizeof(int) * 128);
  int* boff = (int*)alloc(sizeof(int) * 128);
  int* ssrc = (int*)alloc(sizeof(int) * N_EDGES);  // 6.4 MB

  // CSR build (counting sort by dst)
  hipMemsetAsync(counts, 0, sizeof(int) * N_NODES, stream);
  k_count<<<N_EDGES / 256, 256, 0, stream>>>(dst, counts);
  k_scan1<<<N_SCAN_BLOCKS, 256, 0, stream>>>(counts, bsum);
  k_scan2<<<1, 64, 0, stream>>>(bsum, boff, row_ptr, N_SCAN_BLOCKS);
  k_scan3<<<N_SCAN_BLOCKS, 256, 0, stream>>>(counts, boff, row_ptr, cursor, inv_deg);
  k_scatter<<<N_EDGES / 256, 256, 0, stream>>>(src, dst, cursor, ssrc);

  // 3 GIN layers, ping-pong between bufA (t0) and n_embed (t1)
  const float* hin = x;
  float* t0 = bufA;
  float* t1 = n_embed;
  for (int l = 0; l < 3; l++) {
    float* za = (l % 2 == 0) ? t1 : t0;
    float* zb = (l % 2 == 0) ? t0 : t1;
    k_agg<<<N_NODES / 4, 256, 0, stream>>>(hin, za, row_ptr, ssrc, inv_deg, eps, l);
    k_gemm<<<(N_NODES + 127) / 128, 256, 0, stream>>>(za, W1 + (size_t)l * D * D,
                                                      b1 + (size_t)l * D, zb, N_NODES);
    k_gemm<<<(N_NODES + 127) / 128, 256, 0, stream>>>(zb, W2 + (size_t)l * D * D,
                                                      b2 + (size_t)l * D, za, N_NODES);
    hin = za;
  }
  // hin == n_embed here (already in place in d_out)
  k_out<<<N_NODES / 4, 256, 0, stream>>>(n_embed, Wout, bout, out);
}

// Round 3
// 815.811 us; speedup vs baseline: 1.8330x; 1.2330x over previous
//
#include <hip/hip_runtime.h>
#include <math.h>

#define N_NODES 100000
#define N_EDGES 1600000
#define D 128
#define SCAN_CHUNK 1024
#define N_SCAN_BLOCKS 98   // ceil(100000/1024)

typedef short short8_t __attribute__((ext_vector_type(8)));
typedef short short4_t __attribute__((ext_vector_type(4)));
typedef float floatx4 __attribute__((ext_vector_type(4)));

__device__ __forceinline__ unsigned short f32_to_bf16_rne(float f) {
  unsigned u = __builtin_bit_cast(unsigned, f);
  unsigned r = u + 0x7fffu + ((u >> 16) & 1u);
  return (unsigned short)(r >> 16);
}
__device__ __forceinline__ float bf16_bits_to_f32(unsigned short h) {
  return __builtin_bit_cast(float, (unsigned)h << 16);
}

// ---------------- CSR build ----------------

__global__ __launch_bounds__(256) void k_count(const int* __restrict__ dst,
                                               int* __restrict__ counts) {
  int e = blockIdx.x * 256 + threadIdx.x;
  if (e < N_EDGES) atomicAdd(&counts[dst[e]], 1);
}

__global__ __launch_bounds__(256) void k_scan1(const int* __restrict__ counts,
                                               int* __restrict__ bsum) {
  __shared__ int red[256];
  int base = blockIdx.x * SCAN_CHUNK + threadIdx.x * 4;
  int s = 0;
#pragma unroll
  for (int j = 0; j < 4; j++) {
    int i = base + j;
    s += (i < N_NODES) ? counts[i] : 0;
  }
  red[threadIdx.x] = s;
  __syncthreads();
  for (int off = 128; off > 0; off >>= 1) {
    if (threadIdx.x < off) red[threadIdx.x] += red[threadIdx.x + off];
    __syncthreads();
  }
  if (threadIdx.x == 0) bsum[blockIdx.x] = red[0];
}

__global__ void k_scan2(const int* __restrict__ bsum, int* __restrict__ boff,
                        int* __restrict__ row_ptr, int nb) {
  if (threadIdx.x == 0) {
    int run = 0;
    for (int i = 0; i < nb; i++) { boff[i] = run; run += bsum[i]; }
    row_ptr[N_NODES] = run;   // == N_EDGES
  }
}

__global__ __launch_bounds__(256) void k_scan3(const int* __restrict__ counts,
                                               const int* __restrict__ boff,
                                               int* __restrict__ row_ptr,
                                               int* __restrict__ cursor,
                                               float* __restrict__ inv_deg) {
  __shared__ int sd[256];
  int base = blockIdx.x * SCAN_CHUNK + threadIdx.x * 4;
  int c[4];
  int s = 0;
#pragma unroll
  for (int j = 0; j < 4; j++) {
    int i = base + j;
    c[j] = (i < N_NODES) ? counts[i] : 0;
    s += c[j];
  }
  sd[threadIdx.x] = s;
  __syncthreads();
  // inclusive Hillis-Steele scan over 256 thread sums
  for (int off = 1; off < 256; off <<= 1) {
    int add = (threadIdx.x >= off) ? sd[threadIdx.x - off] : 0;
    __syncthreads();
    sd[threadIdx.x] += add;
    __syncthreads();
  }
  int excl = (threadIdx.x ? sd[threadIdx.x - 1] : 0) + boff[blockIdx.x];
#pragma unroll
  for (int j = 0; j < 4; j++) {
    int i = base + j;
    if (i < N_NODES) {
      row_ptr[i] = excl;
      cursor[i] = excl;
      inv_deg[i] = 1.0f / fmaxf((float)c[j], 1.0f);
      excl += c[j];
    }
  }
}

__global__ __launch_bounds__(256) void k_scatter(const int* __restrict__ src,
                                                 const int* __restrict__ dst,
                                                 int* __restrict__ cursor,
                                                 int* __restrict__ ssrc) {
  int e = blockIdx.x * 256 + threadIdx.x;
  if (e < N_EDGES) {
    int pos = atomicAdd(&cursor[dst[e]], 1);
    ssrc[pos] = src[e];
  }
}

// ---------------- GIN aggregation: z = (1+eps)*h + mean_{j in N(i)} h_j ----------------
// One wave per node; lane owns 2 dims (float2); 4-edge unroll for MLP.
__global__ __launch_bounds__(256) void k_agg(const float* __restrict__ h,
                                             float* __restrict__ z,
                                             const int* __restrict__ row_ptr,
                                             const int* __restrict__ ssrc,
                                             const float* __restrict__ inv_deg,
                                             const float* __restrict__ eps,
                                             int layer) {
  int node = blockIdx.x * 4 + (threadIdx.x >> 6);
  int t = threadIdx.x & 63;
  int beg = row_ptr[node];
  int end = row_ptr[node + 1];
  const float* hp = h + 2 * t;
  float ax0 = 0.f, ay0 = 0.f, ax1 = 0.f, ay1 = 0.f;
  float ax2 = 0.f, ay2 = 0.f, ax3 = 0.f, ay3 = 0.f;
  int e = beg;
  for (; e + 4 <= end; e += 4) {
    int i0 = ssrc[e + 0];
    int i1 = ssrc[e + 1];
    int i2 = ssrc[e + 2];
    int i3 = ssrc[e + 3];
    float2 v0 = *(const float2*)(hp + (size_t)i0 * D);
    float2 v1 = *(const float2*)(hp + (size_t)i1 * D);
    float2 v2 = *(const float2*)(hp + (size_t)i2 * D);
    float2 v3 = *(const float2*)(hp + (size_t)i3 * D);
    ax0 += v0.x; ay0 += v0.y;
    ax1 += v1.x; ay1 += v1.y;
    ax2 += v2.x; ay2 += v2.y;
    ax3 += v3.x; ay3 += v3.y;
  }
  for (; e < end; ++e) {
    int i = ssrc[e];
    float2 v = *(const float2*)(hp + (size_t)i * D);
    ax0 += v.x; ay0 += v.y;
  }
  float sx = (ax0 + ax1) + (ax2 + ax3);
  float sy = (ay0 + ay1) + (ay2 + ay3);
  float2 hv = *(const float2*)(hp + (size_t)node * D);
  float ep1 = 1.0f + eps[layer];
  float id = inv_deg[node];
  float2 o;
  o.x = ep1 * hv.x + sx * id;
  o.y = ep1 * hv.y + sy * id;
  *(float2*)(z + (size_t)node * D + 2 * t) = o;
}

// ---------------- W prep: split W[128][128] f32 -> WhT/WlT bf16 [col][k] ----------------
// 6 matrices: y=0..2 -> W1 layer y; y=3..5 -> W2 layer y-3.
// Output layout: WT + mat*2*16384 = hi plane ([col*128+k]), +16384 = lo plane.
__global__ __launch_bounds__(256) void k_wprep(const float* __restrict__ W1,
                                               const float* __restrict__ W2,
                                               short* __restrict__ WT) {
  int mat = blockIdx.y;
  const float* Wsrc = (mat < 3) ? (W1 + (size_t)mat * D * D)
                                : (W2 + (size_t)(mat - 3) * D * D);
  int idx = blockIdx.x * 256 + threadIdx.x;  // 0..16383
  int k = idx >> 7;
  int c = idx & 127;
  float f = Wsrc[idx];
  unsigned short hi = f32_to_bf16_rne(f);
  float lo_f = f - bf16_bits_to_f32(hi);
  unsigned short lo = f32_to_bf16_rne(lo_f);
  short* base = WT + (size_t)mat * 2 * 16384;
  base[c * 128 + k] = (short)hi;
  base[16384 + c * 128 + k] = (short)lo;
}

// ---------------- split-bf16 MFMA GEMM ----------------
// C = leaky_relu(A[nrows,128] @ W[128,128] + b), A f32, W pre-split hi/lo bf16
// transposed [col][k]. A ~= Ah+Al in-register during staging; 3 MFMA terms
// (hh, hl, lh) accumulate into one f32 acc => ~2^-18 relative error.
// Block 128x128, 4 waves 2x2, wave tile 64x64 = 4x4 frags of 16x16x32.
// LDS rows padded to 80B: frag ds_read_b128 is 2-way bank-aliased (free).
#define LDS_STRIDE 40  // shorts per row (32 data + 8 pad) = 80B
__global__ __launch_bounds__(256, 2) void k_gemm(const float* __restrict__ A,
                                                 const short* __restrict__ WhT,
                                                 const short* __restrict__ WlT,
                                                 const float* __restrict__ bias,
                                                 float* __restrict__ C, int nrows) {
  __shared__ short Ah[128 * LDS_STRIDE];
  __shared__ short Al[128 * LDS_STRIDE];
  __shared__ short Wh[128 * LDS_STRIDE];
  __shared__ short Wl[128 * LDS_STRIDE];

  const int tid = threadIdx.x;
  const int row0 = blockIdx.x * 128;
  const int wave = tid >> 6;
  const int lane = tid & 63;
  const int wr = wave >> 1;   // wave row 0..1 (64 rows each)
  const int wc = wave & 1;    // wave col 0..1 (64 cols each)
  const int lr = lane & 15;
  const int koff = lane >> 4; // 0..3 -> k-slot of 8 within 32

  floatx4 acc[4][4];
#pragma unroll
  for (int i = 0; i < 4; i++)
#pragma unroll
    for (int j = 0; j < 4; j++) acc[i][j] = (floatx4)(0.f);

  // A staging: thread -> (row, k-quarter of 16 floats); 4 float4 loads each.
  const int sr = tid >> 1;
  const int skq = tid & 1;
  int arow = row0 + sr;
  if (arow >= nrows) arow = nrows - 1;  // clamped load; stores masked
  const float* Arow = A + (size_t)arow * D;
  // W staging: thread -> (col, k-half of 16 shorts); 2 short8 loads per plane.
  const int swc = tid >> 1;
  const int skh = tid & 1;

  for (int k0 = 0; k0 < 128; k0 += 32) {
    // ---- stage A (f32 -> bf16 hi/lo in registers -> LDS) ----
#pragma unroll
    for (int j = 0; j < 4; j++) {
      float4 av = *(const float4*)(Arow + k0 + skq * 16 + 4 * j);
      float f[4] = {av.x, av.y, av.z, av.w};
      short4_t hi4, lo4;
#pragma unroll
      for (int q = 0; q < 4; q++) {
        unsigned short h = f32_to_bf16_rne(f[q]);
        float lf = f[q] - bf16_bits_to_f32(h);
        hi4[q] = (short)h;
        lo4[q] = (short)f32_to_bf16_rne(lf);
      }
      *(short4_t*)&Ah[sr * LDS_STRIDE + skq * 16 + 4 * j] = hi4;
      *(short4_t*)&Al[sr * LDS_STRIDE + skq * 16 + 4 * j] = lo4;
    }
    // ---- stage W (bf16 planes, already [col][k]) ----
    {
      const short* ph = WhT + swc * 128 + k0 + skh * 16;
      const short* pl = WlT + swc * 128 + k0 + skh * 16;
      short8_t h0 = *(const short8_t*)(ph);
      short8_t h1 = *(const short8_t*)(ph + 8);
      short8_t l0 = *(const short8_t*)(pl);
      short8_t l1 = *(const short8_t*)(pl + 8);
      *(short8_t*)&Wh[swc * LDS_STRIDE + skh * 16] = h0;
      *(short8_t*)&Wh[swc * LDS_STRIDE + skh * 16 + 8] = h1;
      *(short8_t*)&Wl[swc * LDS_STRIDE + skh * 16] = l0;
      *(short8_t*)&Wl[swc * LDS_STRIDE + skh * 16 + 8] = l1;
    }
    __syncthreads();

    // ---- fragments ----
    short8_t ah[4], al[4], wh[4], wl[4];
#pragma unroll
    for (int i = 0; i < 4; i++) {
      int r = wr * 64 + i * 16 + lr;
      ah[i] = *(const short8_t*)&Ah[r * LDS_STRIDE + koff * 8];
      al[i] = *(const short8_t*)&Al[r * LDS_STRIDE + koff * 8];
    }
#pragma unroll
    for (int j = 0; j < 4; j++) {
      int c = wc * 64 + j * 16 + lr;
      wh[j] = *(const short8_t*)&Wh[c * LDS_STRIDE + koff * 8];
      wl[j] = *(const short8_t*)&Wl[c * LDS_STRIDE + koff * 8];
    }
#pragma unroll
    for (int i = 0; i < 4; i++)
#pragma unroll
      for (int j = 0; j < 4; j++) {
        acc[i][j] = __builtin_amdgcn_mfma_f32_16x16x32_bf16(ah[i], wh[j], acc[i][j], 0, 0, 0);
        acc[i][j] = __builtin_amdgcn_mfma_f32_16x16x32_bf16(ah[i], wl[j], acc[i][j], 0, 0, 0);
        acc[i][j] = __builtin_amdgcn_mfma_f32_16x16x32_bf16(al[i], wh[j], acc[i][j], 0, 0, 0);
      }
    __syncthreads();
  }

  // ---- epilogue: bias + leaky_relu, masked f32 stores ----
  float bj[4];
#pragma unroll
  for (int j = 0; j < 4; j++) bj[j] = bias[wc * 64 + j * 16 + lr];
#pragma unroll
  for (int i = 0; i < 4; i++) {
#pragma unroll
    for (int r = 0; r < 4; r++) {
      int row = row0 + wr * 64 + i * 16 + koff * 4 + r;
      if (row < nrows) {
#pragma unroll
        for (int j = 0; j < 4; j++) {
          int col = wc * 64 + j * 16 + lr;
          float v = acc[i][j][r] + bj[j];
          v = v > 0.f ? v : 0.01f * v;
          C[(size_t)row * D + col] = v;
        }
      }
    }
  }
}

// ---------------- output head: n_out = h @ Wout[128,2] + bout ----------------
__global__ __launch_bounds__(256) void k_out(const float* __restrict__ h,
                                             const float* __restrict__ Wout,
                                             const float* __restrict__ bout,
                                             float* __restrict__ out) {
  int node = blockIdx.x * 4 + (threadIdx.x >> 6);
  int lane = threadIdx.x & 63;
  float2 hv = *(const float2*)(h + (size_t)node * D + lane * 2);
  float4 wv = *(const float4*)(Wout + lane * 4);  // Wout[2l][0..1], Wout[2l+1][0..1]
  float p0 = hv.x * wv.x + hv.y * wv.z;
  float p1 = hv.x * wv.y + hv.y * wv.w;
#pragma unroll
  for (int off = 32; off > 0; off >>= 1) {
    p0 += __shfl_down(p0, off, 64);
    p1 += __shfl_down(p1, off, 64);
  }
  if (lane == 0) {
    out[node * 2 + 0] = p0 + bout[0];
    out[node * 2 + 1] = p1 + bout[1];
  }
}

// ---------------- launch ----------------

extern "C" void kernel_launch(void* const* d_in, const int* in_sizes, int n_in,
                              void* d_out, int out_size, void* d_ws, size_t ws_size,
                              hipStream_t stream) {
  const float* x = (const float*)d_in[0];
  const int* src = (const int*)d_in[1];
  const int* dst = (const int*)d_in[2];
  const float* W1 = (const float*)d_in[3];
  const float* b1 = (const float*)d_in[4];
  const float* W2 = (const float*)d_in[5];
  const float* b2 = (const float*)d_in[6];
  const float* eps = (const float*)d_in[7];
  const float* Wout = (const float*)d_in[8];
  const float* bout = (const float*)d_in[9];
  float* out = (float*)d_out;
  float* n_embed = out + (size_t)2 * N_NODES;  // [100000,128] region of d_out

  char* ws = (char*)d_ws;
  size_t off = 0;
  auto alloc = [&](size_t bytes) -> char* {
    char* p = ws + off;
    off += (bytes + 511) & ~(size_t)511;
    return p;
  };
  float* bufA = (float*)alloc(sizeof(float) * (size_t)N_NODES * D);  // 51.2 MB
  int* counts = (int*)alloc(sizeof(int) * N_NODES);
  int* row_ptr = (int*)alloc(sizeof(int) * (N_NODES + 1));
  int* cursor = (int*)alloc(sizeof(int) * N_NODES);
  float* inv_deg = (float*)alloc(sizeof(float) * N_NODES);
  int* bsum = (int*)alloc(sizeof(int) * 128);
  int* boff = (int*)alloc(sizeof(int) * 128);
  int* ssrc = (int*)alloc(sizeof(int) * N_EDGES);          // 6.4 MB
  short* WT = (short*)alloc(sizeof(short) * 6 * 2 * 16384);  // 768 KB

  // CSR build (counting sort by dst)
  hipMemsetAsync(counts, 0, sizeof(int) * N_NODES, stream);
  k_count<<<N_EDGES / 256, 256, 0, stream>>>(dst, counts);
  k_scan1<<<N_SCAN_BLOCKS, 256, 0, stream>>>(counts, bsum);
  k_scan2<<<1, 64, 0, stream>>>(bsum, boff, row_ptr, N_SCAN_BLOCKS);
  k_scan3<<<N_SCAN_BLOCKS, 256, 0, stream>>>(counts, boff, row_ptr, cursor, inv_deg);
  k_scatter<<<N_EDGES / 256, 256, 0, stream>>>(src, dst, cursor, ssrc);

  // W split/transpose (once per launch, all 6 matrices)
  k_wprep<<<dim3(64, 6), 256, 0, stream>>>(W1, W2, WT);

  const int gemm_grid = (N_NODES + 127) / 128;  // 782
  // 3 GIN layers, ping-pong between bufA (t0) and n_embed (t1)
  const float* hin = x;
  float* t0 = bufA;
  float* t1 = n_embed;
  for (int l = 0; l < 3; l++) {
    float* za = (l % 2 == 0) ? t1 : t0;
    float* zb = (l % 2 == 0) ? t0 : t1;
    const short* w1h = WT + (size_t)l * 2 * 16384;        // mat l (W1)
    const short* w1l = w1h + 16384;
    const short* w2h = WT + (size_t)(3 + l) * 2 * 16384;  // mat 3+l (W2)
    const short* w2l = w2h + 16384;
    k_agg<<<N_NODES / 4, 256, 0, stream>>>(hin, za, row_ptr, ssrc, inv_deg, eps, l);
    k_gemm<<<gemm_grid, 256, 0, stream>>>(za, w1h, w1l, b1 + (size_t)l * D, zb, N_NODES);
    k_gemm<<<gemm_grid, 256, 0, stream>>>(zb, w2h, w2l, b2 + (size_t)l * D, za, N_NODES);
    hin = za;
  }
  // hin == n_embed here (already in place in d_out)
  k_out<<<N_NODES / 4, 256, 0, stream>>>(n_embed, Wout, bout, out);
}

// Round 4
// 752.342 us; speedup vs baseline: 1.9877x; 1.0844x over previous
//
#include <hip/hip_runtime.h>
#include <math.h>

#define N_NODES 100000
#define N_EDGES 1600000
#define D 128
#define SCAN_CHUNK 1024
#define N_SCAN_BLOCKS 98   // ceil(100000/1024)
#define N_BUCKETS 98       // dst >> 10
#define EDGES_PER_PART 4096
#define N_PART_BLOCKS ((N_EDGES + EDGES_PER_PART - 1) / EDGES_PER_PART)  // 391

typedef short short8_t __attribute__((ext_vector_type(8)));
typedef short short2_t __attribute__((ext_vector_type(2)));
typedef float floatx4 __attribute__((ext_vector_type(4)));

__device__ __forceinline__ unsigned short f32_to_bf16_rne(float f) {
  unsigned u = __builtin_bit_cast(unsigned, f);
  unsigned r = u + 0x7fffu + ((u >> 16) & 1u);
  return (unsigned short)(r >> 16);
}
__device__ __forceinline__ float bf16_bits_to_f32(unsigned short h) {
  return __builtin_bit_cast(float, (unsigned)h << 16);
}

// ---------------- CSR build ----------------

__global__ __launch_bounds__(256) void k_count(const int* __restrict__ dst,
                                               int* __restrict__ counts) {
  int e = blockIdx.x * 256 + threadIdx.x;
  if (e < N_EDGES) atomicAdd(&counts[dst[e]], 1);
}

__global__ __launch_bounds__(256) void k_scan1(const int* __restrict__ counts,
                                               int* __restrict__ bsum) {
  __shared__ int red[256];
  int base = blockIdx.x * SCAN_CHUNK + threadIdx.x * 4;
  int s = 0;
#pragma unroll
  for (int j = 0; j < 4; j++) {
    int i = base + j;
    s += (i < N_NODES) ? counts[i] : 0;
  }
  red[threadIdx.x] = s;
  __syncthreads();
  for (int off = 128; off > 0; off >>= 1) {
    if (threadIdx.x < off) red[threadIdx.x] += red[threadIdx.x + off];
    __syncthreads();
  }
  if (threadIdx.x == 0) bsum[blockIdx.x] = red[0];
}

__global__ void k_scan2(const int* __restrict__ bsum, int* __restrict__ boff,
                        int* __restrict__ row_ptr, int nb) {
  if (threadIdx.x == 0) {
    int run = 0;
    for (int i = 0; i < nb; i++) { boff[i] = run; run += bsum[i]; }
    row_ptr[N_NODES] = run;   // == N_EDGES
  }
}

__global__ __launch_bounds__(256) void k_scan3(const int* __restrict__ counts,
                                               const int* __restrict__ boff,
                                               int* __restrict__ row_ptr,
                                               float* __restrict__ inv_deg) {
  __shared__ int sd[256];
  int base = blockIdx.x * SCAN_CHUNK + threadIdx.x * 4;
  int c[4];
  int s = 0;
#pragma unroll
  for (int j = 0; j < 4; j++) {
    int i = base + j;
    c[j] = (i < N_NODES) ? counts[i] : 0;
    s += c[j];
  }
  sd[threadIdx.x] = s;
  __syncthreads();
  for (int off = 1; off < 256; off <<= 1) {
    int add = (threadIdx.x >= off) ? sd[threadIdx.x - off] : 0;
    __syncthreads();
    sd[threadIdx.x] += add;
    __syncthreads();
  }
  int excl = (threadIdx.x ? sd[threadIdx.x - 1] : 0) + boff[blockIdx.x];
#pragma unroll
  for (int j = 0; j < 4; j++) {
    int i = base + j;
    if (i < N_NODES) {
      row_ptr[i] = excl;
      inv_deg[i] = 1.0f / fmaxf((float)c[j], 1.0f);
      excl += c[j];
    }
  }
}

__global__ void k_binit(const int* __restrict__ row_ptr,
                        int* __restrict__ bucket_cursor) {
  int t = threadIdx.x;
  if (t < N_BUCKETS) bucket_cursor[t] = row_ptr[t << 10];
}

// Partition pass: LDS-bin 4096 edges into 98 dst-range buckets; write (src,dst)
// pairs in contiguous per-(block,bucket) runs (coalesced; L2-combinable).
__global__ __launch_bounds__(1024) void k_part(const int* __restrict__ src,
                                               const int* __restrict__ dst,
                                               int* __restrict__ bucket_cursor,
                                               int2* __restrict__ ebuf) {
  __shared__ int2 eLDS[EDGES_PER_PART];
  __shared__ int hist[N_BUCKETS];
  __shared__ int lbase[N_BUCKETS];
  __shared__ int lcur[N_BUCKETS];
  __shared__ int gbase[N_BUCKETS];
  const int t = threadIdx.x;
  const int base = blockIdx.x * EDGES_PER_PART;
  const int count = min(EDGES_PER_PART, N_EDGES - base);
  if (t < N_BUCKETS) hist[t] = 0;
  __syncthreads();
  int s[4], d[4];
#pragma unroll
  for (int j = 0; j < 4; j++) {
    int local = j * 1024 + t;
    if (local < count) {
      s[j] = src[base + local];
      d[j] = dst[base + local];
      atomicAdd(&hist[d[j] >> 10], 1);
    } else {
      d[j] = -1;
    }
  }
  __syncthreads();
  if (t == 0) {
    int run = 0;
    for (int b = 0; b < N_BUCKETS; b++) { lbase[b] = run; run += hist[b]; }
  }
  __syncthreads();
  if (t < N_BUCKETS) {
    lcur[t] = lbase[t];
    gbase[t] = hist[t] ? atomicAdd(&bucket_cursor[t], hist[t]) : 0;
  }
  __syncthreads();
#pragma unroll
  for (int j = 0; j < 4; j++) {
    if (d[j] >= 0) {
      int p = atomicAdd(&lcur[d[j] >> 10], 1);
      eLDS[p] = make_int2(s[j], d[j]);
    }
  }
  __syncthreads();
#pragma unroll
  for (int j = 0; j < 4; j++) {
    int slot = j * 1024 + t;
    if (slot < count) {
      int2 e = eLDS[slot];
      int b = e.y >> 10;
      ebuf[gbase[b] + (slot - lbase[b])] = e;
    }
  }
}

// Local sort pass: one block per bucket; scatter src into ssrc positions via
// LDS per-node cursors. Writes land in the bucket's ~64KB window from a single
// CU/XCD -> L2 assembles full lines (kills the 16x write amplification).
__global__ __launch_bounds__(1024) void k_lsort(const int2* __restrict__ ebuf,
                                                const int* __restrict__ row_ptr,
                                                int* __restrict__ ssrc) {
  __shared__ int lcur[1024];
  const int b = blockIdx.x;
  const int t = threadIdx.x;
  const int node_base = b << 10;
  const int nb = min(1024, N_NODES - node_base);
  if (t < nb) lcur[t] = row_ptr[node_base + t];
  __syncthreads();
  const int rbeg = row_ptr[node_base];
  const int rend = row_ptr[node_base + nb];
  for (int i = rbeg + t; i < rend; i += 1024) {
    int2 e = ebuf[i];
    int p = atomicAdd(&lcur[e.y - node_base], 1);
    ssrc[p] = e.x;
  }
}

// ---------------- GIN aggregation: z = (1+eps)*h + mean_{j in N(i)} h_j ----------------
// One wave per node; lane owns 2 dims; 4-edge unroll for MLP.
// Epilogue splits z into bf16 hi/lo planes (feeds the MFMA GEMMs copy-only).
__global__ __launch_bounds__(256) void k_agg(const float* __restrict__ h,
                                             short* __restrict__ zh,
                                             short* __restrict__ zl,
                                             const int* __restrict__ row_ptr,
                                             const int* __restrict__ ssrc,
                                             const float* __restrict__ inv_deg,
                                             const float* __restrict__ eps,
                                             int layer) {
  int node = blockIdx.x * 4 + (threadIdx.x >> 6);
  int t = threadIdx.x & 63;
  int beg = row_ptr[node];
  int end = row_ptr[node + 1];
  const float* hp = h + 2 * t;
  float ax0 = 0.f, ay0 = 0.f, ax1 = 0.f, ay1 = 0.f;
  float ax2 = 0.f, ay2 = 0.f, ax3 = 0.f, ay3 = 0.f;
  int e = beg;
  for (; e + 4 <= end; e += 4) {
    int i0 = ssrc[e + 0];
    int i1 = ssrc[e + 1];
    int i2 = ssrc[e + 2];
    int i3 = ssrc[e + 3];
    float2 v0 = *(const float2*)(hp + (size_t)i0 * D);
    float2 v1 = *(const float2*)(hp + (size_t)i1 * D);
    float2 v2 = *(const float2*)(hp + (size_t)i2 * D);
    float2 v3 = *(const float2*)(hp + (size_t)i3 * D);
    ax0 += v0.x; ay0 += v0.y;
    ax1 += v1.x; ay1 += v1.y;
    ax2 += v2.x; ay2 += v2.y;
    ax3 += v3.x; ay3 += v3.y;
  }
  for (; e < end; ++e) {
    int i = ssrc[e];
    float2 v = *(const float2*)(hp + (size_t)i * D);
    ax0 += v.x; ay0 += v.y;
  }
  float sx = (ax0 + ax1) + (ax2 + ax3);
  float sy = (ay0 + ay1) + (ay2 + ay3);
  float2 hv = *(const float2*)(hp + (size_t)node * D);
  float ep1 = 1.0f + eps[layer];
  float id = inv_deg[node];
  float zx = ep1 * hv.x + sx * id;
  float zy = ep1 * hv.y + sy * id;
  unsigned short hx = f32_to_bf16_rne(zx);
  unsigned short hy = f32_to_bf16_rne(zy);
  unsigned short lx = f32_to_bf16_rne(zx - bf16_bits_to_f32(hx));
  unsigned short ly = f32_to_bf16_rne(zy - bf16_bits_to_f32(hy));
  short2_t hw, lw;
  hw[0] = (short)hx; hw[1] = (short)hy;
  lw[0] = (short)lx; lw[1] = (short)ly;
  *(short2_t*)&zh[(size_t)node * D + 2 * t] = hw;
  *(short2_t*)&zl[(size_t)node * D + 2 * t] = lw;
}

// ---------------- W prep: split W[128][128] f32 -> WhT/WlT bf16 [col][k] ----------------
__global__ __launch_bounds__(256) void k_wprep(const float* __restrict__ W1,
                                               const float* __restrict__ W2,
                                               short* __restrict__ WT) {
  int mat = blockIdx.y;
  const float* Wsrc = (mat < 3) ? (W1 + (size_t)mat * D * D)
                                : (W2 + (size_t)(mat - 3) * D * D);
  int idx = blockIdx.x * 256 + threadIdx.x;  // 0..16383
  int k = idx >> 7;
  int c = idx & 127;
  float f = Wsrc[idx];
  unsigned short hi = f32_to_bf16_rne(f);
  float lo_f = f - bf16_bits_to_f32(hi);
  unsigned short lo = f32_to_bf16_rne(lo_f);
  short* base = WT + (size_t)mat * 2 * 16384;
  base[c * 128 + k] = (short)hi;
  base[16384 + c * 128 + k] = (short)lo;
}

// ---------------- split-bf16 MFMA GEMM, plane inputs ----------------
// A given as bf16 hi/lo planes [row][k]; W pre-split [col][k]. Staging is pure
// vector copy (no conversion VALU in the k-loop). 3 MFMA terms (hh, hl, lh).
// Block 128x128, 4 waves 2x2, wave tile 64x64 = 4x4 frags of 16x16x32.
// plane_out=1: epilogue splits result into hi/lo planes (in-place over A planes
// is safe: block reads only its own 128 rows, all reads complete before the
// final barrier). plane_out=0: f32 output.
#define LDS_STRIDE 40  // shorts per row (32 data + 8 pad) = 80B; frag reads 2-way (free)
__global__ __launch_bounds__(256, 2) void k_gemm(const short* __restrict__ Aph,
                                                 const short* __restrict__ Apl,
                                                 const short* __restrict__ WhT,
                                                 const short* __restrict__ WlT,
                                                 const float* __restrict__ bias,
                                                 float* __restrict__ Cf,
                                                 short* __restrict__ Cph,
                                                 short* __restrict__ Cpl,
                                                 int nrows, int plane_out) {
  __shared__ short Ah[128 * LDS_STRIDE];
  __shared__ short Al[128 * LDS_STRIDE];
  __shared__ short Wh[128 * LDS_STRIDE];
  __shared__ short Wl[128 * LDS_STRIDE];

  const int tid = threadIdx.x;
  const int row0 = blockIdx.x * 128;
  const int wave = tid >> 6;
  const int lane = tid & 63;
  const int wr = wave >> 1;
  const int wc = wave & 1;
  const int lr = lane & 15;
  const int koff = lane >> 4;

  floatx4 acc[4][4];
#pragma unroll
  for (int i = 0; i < 4; i++)
#pragma unroll
    for (int j = 0; j < 4; j++) acc[i][j] = (floatx4)(0.f);

  // staging: thread -> (row/col = tid>>1, k-half sa = 0 or 16 shorts)
  const int rs = tid >> 1;
  const int sa = (tid & 1) * 16;
  int arow = row0 + rs;
  if (arow >= nrows) arow = nrows - 1;
  const short* pAh = Aph + (size_t)arow * D;
  const short* pAl = Apl + (size_t)arow * D;
  const short* pWh = WhT + (size_t)rs * D;
  const short* pWl = WlT + (size_t)rs * D;

  for (int k0 = 0; k0 < 128; k0 += 32) {
    short8_t a0 = *(const short8_t*)(pAh + k0 + sa);
    short8_t a1 = *(const short8_t*)(pAh + k0 + sa + 8);
    short8_t b0 = *(const short8_t*)(pAl + k0 + sa);
    short8_t b1 = *(const short8_t*)(pAl + k0 + sa + 8);
    short8_t w0 = *(const short8_t*)(pWh + k0 + sa);
    short8_t w1 = *(const short8_t*)(pWh + k0 + sa + 8);
    short8_t x0 = *(const short8_t*)(pWl + k0 + sa);
    short8_t x1 = *(const short8_t*)(pWl + k0 + sa + 8);
    *(short8_t*)&Ah[rs * LDS_STRIDE + sa] = a0;
    *(short8_t*)&Ah[rs * LDS_STRIDE + sa + 8] = a1;
    *(short8_t*)&Al[rs * LDS_STRIDE + sa] = b0;
    *(short8_t*)&Al[rs * LDS_STRIDE + sa + 8] = b1;
    *(short8_t*)&Wh[rs * LDS_STRIDE + sa] = w0;
    *(short8_t*)&Wh[rs * LDS_STRIDE + sa + 8] = w1;
    *(short8_t*)&Wl[rs * LDS_STRIDE + sa] = x0;
    *(short8_t*)&Wl[rs * LDS_STRIDE + sa + 8] = x1;
    __syncthreads();

    short8_t ah[4], al[4], wh[4], wl[4];
#pragma unroll
    for (int i = 0; i < 4; i++) {
      int r = wr * 64 + i * 16 + lr;
      ah[i] = *(const short8_t*)&Ah[r * LDS_STRIDE + koff * 8];
      al[i] = *(const short8_t*)&Al[r * LDS_STRIDE + koff * 8];
    }
#pragma unroll
    for (int j = 0; j < 4; j++) {
      int c = wc * 64 + j * 16 + lr;
      wh[j] = *(const short8_t*)&Wh[c * LDS_STRIDE + koff * 8];
      wl[j] = *(const short8_t*)&Wl[c * LDS_STRIDE + koff * 8];
    }
#pragma unroll
    for (int i = 0; i < 4; i++)
#pragma unroll
      for (int j = 0; j < 4; j++) {
        acc[i][j] = __builtin_amdgcn_mfma_f32_16x16x32_bf16(ah[i], wh[j], acc[i][j], 0, 0, 0);
        acc[i][j] = __builtin_amdgcn_mfma_f32_16x16x32_bf16(ah[i], wl[j], acc[i][j], 0, 0, 0);
        acc[i][j] = __builtin_amdgcn_mfma_f32_16x16x32_bf16(al[i], wh[j], acc[i][j], 0, 0, 0);
      }
    __syncthreads();
  }

  // ---- epilogue: bias + leaky_relu ----
  float bj[4];
#pragma unroll
  for (int j = 0; j < 4; j++) bj[j] = bias[wc * 64 + j * 16 + lr];
  if (plane_out) {
#pragma unroll
    for (int i = 0; i < 4; i++) {
#pragma unroll
      for (int r = 0; r < 4; r++) {
        int row = row0 + wr * 64 + i * 16 + koff * 4 + r;
        if (row < nrows) {
#pragma unroll
          for (int j = 0; j < 4; j++) {
            int col = wc * 64 + j * 16 + lr;
            float v = acc[i][j][r] + bj[j];
            v = v > 0.f ? v : 0.01f * v;
            unsigned short hv = f32_to_bf16_rne(v);
            unsigned short lv = f32_to_bf16_rne(v - bf16_bits_to_f32(hv));
            Cph[(size_t)row * D + col] = (short)hv;
            Cpl[(size_t)row * D + col] = (short)lv;
          }
        }
      }
    }
  } else {
#pragma unroll
    for (int i = 0; i < 4; i++) {
#pragma unroll
      for (int r = 0; r < 4; r++) {
        int row = row0 + wr * 64 + i * 16 + koff * 4 + r;
        if (row < nrows) {
#pragma unroll
          for (int j = 0; j < 4; j++) {
            int col = wc * 64 + j * 16 + lr;
            float v = acc[i][j][r] + bj[j];
            v = v > 0.f ? v : 0.01f * v;
            Cf[(size_t)row * D + col] = v;
          }
        }
      }
    }
  }
}

// ---------------- output head: n_out = h @ Wout[128,2] + bout ----------------
__global__ __launch_bounds__(256) void k_out(const float* __restrict__ h,
                                             const float* __restrict__ Wout,
                                             const float* __restrict__ bout,
                                             float* __restrict__ out) {
  int node = blockIdx.x * 4 + (threadIdx.x >> 6);
  int lane = threadIdx.x & 63;
  float2 hv = *(const float2*)(h + (size_t)node * D + lane * 2);
  float4 wv = *(const float4*)(Wout + lane * 4);
  float p0 = hv.x * wv.x + hv.y * wv.z;
  float p1 = hv.x * wv.y + hv.y * wv.w;
#pragma unroll
  for (int off = 32; off > 0; off >>= 1) {
    p0 += __shfl_down(p0, off, 64);
    p1 += __shfl_down(p1, off, 64);
  }
  if (lane == 0) {
    out[node * 2 + 0] = p0 + bout[0];
    out[node * 2 + 1] = p1 + bout[1];
  }
}

// ---------------- launch ----------------

extern "C" void kernel_launch(void* const* d_in, const int* in_sizes, int n_in,
                              void* d_out, int out_size, void* d_ws, size_t ws_size,
                              hipStream_t stream) {
  const float* x = (const float*)d_in[0];
  const int* src = (const int*)d_in[1];
  const int* dst = (const int*)d_in[2];
  const float* W1 = (const float*)d_in[3];
  const float* b1 = (const float*)d_in[4];
  const float* W2 = (const float*)d_in[5];
  const float* b2 = (const float*)d_in[6];
  const float* eps = (const float*)d_in[7];
  const float* Wout = (const float*)d_in[8];
  const float* bout = (const float*)d_in[9];
  float* out = (float*)d_out;
  float* n_embed = out + (size_t)2 * N_NODES;  // f32 h lives here between kernels

  char* ws = (char*)d_ws;
  size_t off = 0;
  auto alloc = [&](size_t bytes) -> char* {
    char* p = ws + off;
    off += (bytes + 511) & ~(size_t)511;
    return p;
  };
  short* zh = (short*)alloc(sizeof(short) * (size_t)N_NODES * D);  // 25.6 MB
  short* zl = (short*)alloc(sizeof(short) * (size_t)N_NODES * D);  // 25.6 MB
  int* ssrc = (int*)alloc(sizeof(int) * N_EDGES);                  // 6.4 MB
  int* counts = (int*)alloc(sizeof(int) * N_NODES);
  int* row_ptr = (int*)alloc(sizeof(int) * (N_NODES + 1));
  float* inv_deg = (float*)alloc(sizeof(float) * N_NODES);
  int* bsum = (int*)alloc(sizeof(int) * 128);
  int* boff = (int*)alloc(sizeof(int) * 128);
  int* bucket_cursor = (int*)alloc(sizeof(int) * 128);
  short* WT = (short*)alloc(sizeof(short) * 6 * 2 * 16384);        // 768 KB
  // ebuf (12.8 MB) aliases the plane buffers: dead before the first k_agg.
  int2* ebuf = (int2*)zh;

  // CSR build: count -> scan -> partition -> bucket-local sort
  hipMemsetAsync(counts, 0, sizeof(int) * N_NODES, stream);
  k_count<<<N_EDGES / 256, 256, 0, stream>>>(dst, counts);
  k_scan1<<<N_SCAN_BLOCKS, 256, 0, stream>>>(counts, bsum);
  k_scan2<<<1, 64, 0, stream>>>(bsum, boff, row_ptr, N_SCAN_BLOCKS);
  k_scan3<<<N_SCAN_BLOCKS, 256, 0, stream>>>(counts, boff, row_ptr, inv_deg);
  k_binit<<<1, 128, 0, stream>>>(row_ptr, bucket_cursor);
  k_part<<<N_PART_BLOCKS, 1024, 0, stream>>>(src, dst, bucket_cursor, ebuf);
  k_lsort<<<N_BUCKETS, 1024, 0, stream>>>(ebuf, row_ptr, ssrc);

  // W split/transpose (all 6 matrices)
  k_wprep<<<dim3(64, 6), 256, 0, stream>>>(W1, W2, WT);

  const int gemm_grid = (N_NODES + 127) / 128;  // 782
  // Per layer: agg(h -> planes); gemm1(planes -> planes, in-place); gemm2(planes -> h f32)
  // f32 h always lives in the n_embed region (fully consumed by agg before gemm2 rewrites).
  for (int l = 0; l < 3; l++) {
    const float* hin = (l == 0) ? x : n_embed;
    const short* w1h = WT + (size_t)l * 2 * 16384;
    const short* w1l = w1h + 16384;
    const short* w2h = WT + (size_t)(3 + l) * 2 * 16384;
    const short* w2l = w2h + 16384;
    k_agg<<<N_NODES / 4, 256, 0, stream>>>(hin, zh, zl, row_ptr, ssrc, inv_deg, eps, l);
    k_gemm<<<gemm_grid, 256, 0, stream>>>(zh, zl, w1h, w1l, b1 + (size_t)l * D,
                                          (float*)nullptr, zh, zl, N_NODES, 1);
    k_gemm<<<gemm_grid, 256, 0, stream>>>(zh, zl, w2h, w2l, b2 + (size_t)l * D,
                                          n_embed, (short*)nullptr, (short*)nullptr,
                                          N_NODES, 0);
  }
  k_out<<<N_NODES / 4, 256, 0, stream>>>(n_embed, Wout, bout, out);
}

// Round 7
// 750.117 us; speedup vs baseline: 1.9936x; 1.0030x over previous
//
#include <hip/hip_runtime.h>
#include <math.h>

#define N_NODES 100000
#define N_EDGES 1600000
#define D 128
#define SCAN_CHUNK 1024
#define N_SCAN_BLOCKS 98   // ceil(100000/1024)
#define N_BUCKETS 98       // dst >> 10
#define EDGES_PER_PART 4096
#define N_PART_BLOCKS ((N_EDGES + EDGES_PER_PART - 1) / EDGES_PER_PART)  // 391

typedef short short8_t __attribute__((ext_vector_type(8)));
typedef short short4_t __attribute__((ext_vector_type(4)));
typedef short short2_t __attribute__((ext_vector_type(2)));
typedef float floatx4 __attribute__((ext_vector_type(4)));

__device__ __forceinline__ unsigned short f32_to_bf16_rne(float f) {
  unsigned u = __builtin_bit_cast(unsigned, f);
  unsigned r = u + 0x7fffu + ((u >> 16) & 1u);
  return (unsigned short)(r >> 16);
}
__device__ __forceinline__ float bf16_bits_to_f32(unsigned short h) {
  return __builtin_bit_cast(float, (unsigned)h << 16);
}

// ---------------- CSR build ----------------

__global__ __launch_bounds__(256) void k_count(const int* __restrict__ dst,
                                               int* __restrict__ counts) {
  int e = blockIdx.x * 256 + threadIdx.x;
  if (e < N_EDGES) atomicAdd(&counts[dst[e]], 1);
}

__global__ __launch_bounds__(256) void k_scan1(const int* __restrict__ counts,
                                               int* __restrict__ bsum) {
  __shared__ int red[256];
  int base = blockIdx.x * SCAN_CHUNK + threadIdx.x * 4;
  int s = 0;
#pragma unroll
  for (int j = 0; j < 4; j++) {
    int i = base + j;
    s += (i < N_NODES) ? counts[i] : 0;
  }
  red[threadIdx.x] = s;
  __syncthreads();
  for (int off = 128; off > 0; off >>= 1) {
    if (threadIdx.x < off) red[threadIdx.x] += red[threadIdx.x + off];
    __syncthreads();
  }
  if (threadIdx.x == 0) bsum[blockIdx.x] = red[0];
}

__global__ void k_scan2(const int* __restrict__ bsum, int* __restrict__ boff,
                        int* __restrict__ row_ptr, int nb) {
  if (threadIdx.x == 0) {
    int run = 0;
    for (int i = 0; i < nb; i++) { boff[i] = run; run += bsum[i]; }
    row_ptr[N_NODES] = run;   // == N_EDGES
  }
}

__global__ __launch_bounds__(256) void k_scan3(const int* __restrict__ counts,
                                               const int* __restrict__ boff,
                                               int* __restrict__ row_ptr,
                                               float* __restrict__ inv_deg) {
  __shared__ int sd[256];
  int base = blockIdx.x * SCAN_CHUNK + threadIdx.x * 4;
  int c[4];
  int s = 0;
#pragma unroll
  for (int j = 0; j < 4; j++) {
    int i = base + j;
    c[j] = (i < N_NODES) ? counts[i] : 0;
    s += c[j];
  }
  sd[threadIdx.x] = s;
  __syncthreads();
  for (int off = 1; off < 256; off <<= 1) {
    int add = (threadIdx.x >= off) ? sd[threadIdx.x - off] : 0;
    __syncthreads();
    sd[threadIdx.x] += add;
    __syncthreads();
  }
  int excl = (threadIdx.x ? sd[threadIdx.x - 1] : 0) + boff[blockIdx.x];
#pragma unroll
  for (int j = 0; j < 4; j++) {
    int i = base + j;
    if (i < N_NODES) {
      row_ptr[i] = excl;
      inv_deg[i] = 1.0f / fmaxf((float)c[j], 1.0f);
      excl += c[j];
    }
  }
}

__global__ void k_binit(const int* __restrict__ row_ptr,
                        int* __restrict__ bucket_cursor) {
  int t = threadIdx.x;
  if (t < N_BUCKETS) bucket_cursor[t] = row_ptr[t << 10];
}

// Partition pass: LDS-bin 4096 edges into 98 dst-range buckets; write (src,dst)
// pairs in contiguous per-(block,bucket) runs (coalesced; L2-combinable).
__global__ __launch_bounds__(1024) void k_part(const int* __restrict__ src,
                                               const int* __restrict__ dst,
                                               int* __restrict__ bucket_cursor,
                                               int2* __restrict__ ebuf) {
  __shared__ int2 eLDS[EDGES_PER_PART];
  __shared__ int hist[N_BUCKETS];
  __shared__ int lbase[N_BUCKETS];
  __shared__ int lcur[N_BUCKETS];
  __shared__ int gbase[N_BUCKETS];
  const int t = threadIdx.x;
  const int base = blockIdx.x * EDGES_PER_PART;
  const int count = min(EDGES_PER_PART, N_EDGES - base);
  if (t < N_BUCKETS) hist[t] = 0;
  __syncthreads();
  int s[4], d[4];
#pragma unroll
  for (int j = 0; j < 4; j++) {
    int local = j * 1024 + t;
    if (local < count) {
      s[j] = src[base + local];
      d[j] = dst[base + local];
      atomicAdd(&hist[d[j] >> 10], 1);
    } else {
      d[j] = -1;
    }
  }
  __syncthreads();
  if (t == 0) {
    int run = 0;
    for (int b = 0; b < N_BUCKETS; b++) { lbase[b] = run; run += hist[b]; }
  }
  __syncthreads();
  if (t < N_BUCKETS) {
    lcur[t] = lbase[t];
    gbase[t] = hist[t] ? atomicAdd(&bucket_cursor[t], hist[t]) : 0;
  }
  __syncthreads();
#pragma unroll
  for (int j = 0; j < 4; j++) {
    if (d[j] >= 0) {
      int p = atomicAdd(&lcur[d[j] >> 10], 1);
      eLDS[p] = make_int2(s[j], d[j]);
    }
  }
  __syncthreads();
#pragma unroll
  for (int j = 0; j < 4; j++) {
    int slot = j * 1024 + t;
    if (slot < count) {
      int2 e = eLDS[slot];
      int b = e.y >> 10;
      ebuf[gbase[b] + (slot - lbase[b])] = e;
    }
  }
}

// Local sort pass: one block per bucket; scatter src into ssrc positions via
// LDS per-node cursors. Writes land in the bucket's ~64KB window from a single
// CU/XCD -> L2 assembles full lines (kills the 16x write amplification).
__global__ __launch_bounds__(1024) void k_lsort(const int2* __restrict__ ebuf,
                                                const int* __restrict__ row_ptr,
                                                int* __restrict__ ssrc) {
  __shared__ int lcur[1024];
  const int b = blockIdx.x;
  const int t = threadIdx.x;
  const int node_base = b << 10;
  const int nb = min(1024, N_NODES - node_base);
  if (t < nb) lcur[t] = row_ptr[node_base + t];
  __syncthreads();
  const int rbeg = row_ptr[node_base];
  const int rend = row_ptr[node_base + nb];
  for (int i = rbeg + t; i < rend; i += 1024) {
    int2 e = ebuf[i];
    int p = atomicAdd(&lcur[e.y - node_base], 1);
    ssrc[p] = e.x;
  }
}

// ---------------- GIN aggregation: z = (1+eps)*h + mean_{j in N(i)} h_j ----------------
// R4-exact version (known-pass): one wave per node; lane owns 2 dims (float2);
// 4-edge unroll for MLP. Epilogue splits z into bf16 hi/lo planes.
// [R6 bisect: the R5 shfl-broadcast rewrite produced a sparse 4.9e-3 error on
//  n_embed; reverted to this verified version while keeping the GEMM prefetch.]
__global__ __launch_bounds__(256) void k_agg(const float* __restrict__ h,
                                             short* __restrict__ zh,
                                             short* __restrict__ zl,
                                             const int* __restrict__ row_ptr,
                                             const int* __restrict__ ssrc,
                                             const float* __restrict__ inv_deg,
                                             const float* __restrict__ eps,
                                             int layer) {
  int node = blockIdx.x * 4 + (threadIdx.x >> 6);
  int t = threadIdx.x & 63;
  int beg = row_ptr[node];
  int end = row_ptr[node + 1];
  const float* hp = h + 2 * t;
  float ax0 = 0.f, ay0 = 0.f, ax1 = 0.f, ay1 = 0.f;
  float ax2 = 0.f, ay2 = 0.f, ax3 = 0.f, ay3 = 0.f;
  int e = beg;
  for (; e + 4 <= end; e += 4) {
    int i0 = ssrc[e + 0];
    int i1 = ssrc[e + 1];
    int i2 = ssrc[e + 2];
    int i3 = ssrc[e + 3];
    float2 v0 = *(const float2*)(hp + (size_t)i0 * D);
    float2 v1 = *(const float2*)(hp + (size_t)i1 * D);
    float2 v2 = *(const float2*)(hp + (size_t)i2 * D);
    float2 v3 = *(const float2*)(hp + (size_t)i3 * D);
    ax0 += v0.x; ay0 += v0.y;
    ax1 += v1.x; ay1 += v1.y;
    ax2 += v2.x; ay2 += v2.y;
    ax3 += v3.x; ay3 += v3.y;
  }
  for (; e < end; ++e) {
    int i = ssrc[e];
    float2 v = *(const float2*)(hp + (size_t)i * D);
    ax0 += v.x; ay0 += v.y;
  }
  float sx = (ax0 + ax1) + (ax2 + ax3);
  float sy = (ay0 + ay1) + (ay2 + ay3);
  float2 hv = *(const float2*)(hp + (size_t)node * D);
  float ep1 = 1.0f + eps[layer];
  float id = inv_deg[node];
  float zx = ep1 * hv.x + sx * id;
  float zy = ep1 * hv.y + sy * id;
  unsigned short hx = f32_to_bf16_rne(zx);
  unsigned short hy = f32_to_bf16_rne(zy);
  unsigned short lx = f32_to_bf16_rne(zx - bf16_bits_to_f32(hx));
  unsigned short ly = f32_to_bf16_rne(zy - bf16_bits_to_f32(hy));
  short2_t hw, lw;
  hw[0] = (short)hx; hw[1] = (short)hy;
  lw[0] = (short)lx; lw[1] = (short)ly;
  *(short2_t*)&zh[(size_t)node * D + 2 * t] = hw;
  *(short2_t*)&zl[(size_t)node * D + 2 * t] = lw;
}

// ---------------- W prep: split W[128][128] f32 -> WhT/WlT bf16 [col][k] ----------------
__global__ __launch_bounds__(256) void k_wprep(const float* __restrict__ W1,
                                               const float* __restrict__ W2,
                                               short* __restrict__ WT) {
  int mat = blockIdx.y;
  const float* Wsrc = (mat < 3) ? (W1 + (size_t)mat * D * D)
                                : (W2 + (size_t)(mat - 3) * D * D);
  int idx = blockIdx.x * 256 + threadIdx.x;  // 0..16383
  int k = idx >> 7;
  int c = idx & 127;
  float f = Wsrc[idx];
  unsigned short hi = f32_to_bf16_rne(f);
  float lo_f = f - bf16_bits_to_f32(hi);
  unsigned short lo = f32_to_bf16_rne(lo_f);
  short* base = WT + (size_t)mat * 2 * 16384;
  base[c * 128 + k] = (short)hi;
  base[16384 + c * 128 + k] = (short)lo;
}

// ---------------- split-bf16 MFMA GEMM, plane inputs, reg-prefetched K-loop ----------------
// A as bf16 hi/lo planes [row][k]; W pre-split [col][k]. 3 MFMA terms (hh,hl,lh).
// Block 128x128, 4 waves 2x2, wave tile 64x64 = 4x4 frags of 16x16x32.
// Next K-tile's 8 short8 are prefetched into registers right after the first
// barrier, hiding global latency under frag reads + 48 MFMAs.
#define LDS_STRIDE 40  // shorts per row (32 data + 8 pad) = 80B; frag reads 2-way (free)
__global__ __launch_bounds__(256, 2) void k_gemm(const short* __restrict__ Aph,
                                                 const short* __restrict__ Apl,
                                                 const short* __restrict__ WhT,
                                                 const short* __restrict__ WlT,
                                                 const float* __restrict__ bias,
                                                 float* __restrict__ Cf,
                                                 short* __restrict__ Cph,
                                                 short* __restrict__ Cpl,
                                                 int nrows, int plane_out) {
  __shared__ short Ah[128 * LDS_STRIDE];
  __shared__ short Al[128 * LDS_STRIDE];
  __shared__ short Wh[128 * LDS_STRIDE];
  __shared__ short Wl[128 * LDS_STRIDE];

  const int tid = threadIdx.x;
  const int row0 = blockIdx.x * 128;
  const int wave = tid >> 6;
  const int lane = tid & 63;
  const int wr = wave >> 1;
  const int wc = wave & 1;
  const int lr = lane & 15;
  const int koff = lane >> 4;

  floatx4 acc[4][4];
#pragma unroll
  for (int i = 0; i < 4; i++)
#pragma unroll
    for (int j = 0; j < 4; j++) acc[i][j] = (floatx4)(0.f);

  // staging: thread -> (row/col = tid>>1, k-half sa = 0 or 16 shorts)
  const int rs = tid >> 1;
  const int sa = (tid & 1) * 16;
  int arow = row0 + rs;
  if (arow >= nrows) arow = nrows - 1;
  const short* pAh = Aph + (size_t)arow * D;
  const short* pAl = Apl + (size_t)arow * D;
  const short* pWh = WhT + (size_t)rs * D;
  const short* pWl = WlT + (size_t)rs * D;

  short8_t rAh0, rAh1, rAl0, rAl1, rWh0, rWh1, rWl0, rWl1;
#define LOADREGS(K0)                                      \
  do {                                                    \
    rAh0 = *(const short8_t*)(pAh + (K0) + sa);           \
    rAh1 = *(const short8_t*)(pAh + (K0) + sa + 8);       \
    rAl0 = *(const short8_t*)(pAl + (K0) + sa);           \
    rAl1 = *(const short8_t*)(pAl + (K0) + sa + 8);       \
    rWh0 = *(const short8_t*)(pWh + (K0) + sa);           \
    rWh1 = *(const short8_t*)(pWh + (K0) + sa + 8);       \
    rWl0 = *(const short8_t*)(pWl + (K0) + sa);           \
    rWl1 = *(const short8_t*)(pWl + (K0) + sa + 8);       \
  } while (0)

  LOADREGS(0);
#pragma unroll
  for (int k0 = 0; k0 < 128; k0 += 32) {
    *(short8_t*)&Ah[rs * LDS_STRIDE + sa] = rAh0;
    *(short8_t*)&Ah[rs * LDS_STRIDE + sa + 8] = rAh1;
    *(short8_t*)&Al[rs * LDS_STRIDE + sa] = rAl0;
    *(short8_t*)&Al[rs * LDS_STRIDE + sa + 8] = rAl1;
    *(short8_t*)&Wh[rs * LDS_STRIDE + sa] = rWh0;
    *(short8_t*)&Wh[rs * LDS_STRIDE + sa + 8] = rWh1;
    *(short8_t*)&Wl[rs * LDS_STRIDE + sa] = rWl0;
    *(short8_t*)&Wl[rs * LDS_STRIDE + sa + 8] = rWl1;
    __syncthreads();
    if (k0 < 96) LOADREGS(k0 + 32);  // prefetch next tile under compute

    short8_t ah[4], al[4], wh[4], wl[4];
#pragma unroll
    for (int i = 0; i < 4; i++) {
      int r = wr * 64 + i * 16 + lr;
      ah[i] = *(const short8_t*)&Ah[r * LDS_STRIDE + koff * 8];
      al[i] = *(const short8_t*)&Al[r * LDS_STRIDE + koff * 8];
    }
#pragma unroll
    for (int j = 0; j < 4; j++) {
      int c = wc * 64 + j * 16 + lr;
      wh[j] = *(const short8_t*)&Wh[c * LDS_STRIDE + koff * 8];
      wl[j] = *(const short8_t*)&Wl[c * LDS_STRIDE + koff * 8];
    }
#pragma unroll
    for (int i = 0; i < 4; i++)
#pragma unroll
      for (int j = 0; j < 4; j++) {
        acc[i][j] = __builtin_amdgcn_mfma_f32_16x16x32_bf16(ah[i], wh[j], acc[i][j], 0, 0, 0);
        acc[i][j] = __builtin_amdgcn_mfma_f32_16x16x32_bf16(ah[i], wl[j], acc[i][j], 0, 0, 0);
        acc[i][j] = __builtin_amdgcn_mfma_f32_16x16x32_bf16(al[i], wh[j], acc[i][j], 0, 0, 0);
      }
    __syncthreads();
  }
#undef LOADREGS

  // ---- epilogue: bias + leaky_relu ----
  float bj[4];
#pragma unroll
  for (int j = 0; j < 4; j++) bj[j] = bias[wc * 64 + j * 16 + lr];
  if (plane_out) {
#pragma unroll
    for (int i = 0; i < 4; i++) {
#pragma unroll
      for (int r = 0; r < 4; r++) {
        int row = row0 + wr * 64 + i * 16 + koff * 4 + r;
        if (row < nrows) {
#pragma unroll
          for (int j = 0; j < 4; j++) {
            int col = wc * 64 + j * 16 + lr;
            float v = acc[i][j][r] + bj[j];
            v = v > 0.f ? v : 0.01f * v;
            unsigned short hv = f32_to_bf16_rne(v);
            unsigned short lv = f32_to_bf16_rne(v - bf16_bits_to_f32(hv));
            Cph[(size_t)row * D + col] = (short)hv;
            Cpl[(size_t)row * D + col] = (short)lv;
          }
        }
      }
    }
  } else {
#pragma unroll
    for (int i = 0; i < 4; i++) {
#pragma unroll
      for (int r = 0; r < 4; r++) {
        int row = row0 + wr * 64 + i * 16 + koff * 4 + r;
        if (row < nrows) {
#pragma unroll
          for (int j = 0; j < 4; j++) {
            int col = wc * 64 + j * 16 + lr;
            float v = acc[i][j][r] + bj[j];
            v = v > 0.f ? v : 0.01f * v;
            Cf[(size_t)row * D + col] = v;
          }
        }
      }
    }
  }
}

// ---------------- output head: n_out = h @ Wout[128,2] + bout ----------------
__global__ __launch_bounds__(256) void k_out(const float* __restrict__ h,
                                             const float* __restrict__ Wout,
                                             const float* __restrict__ bout,
                                             float* __restrict__ out) {
  int node = blockIdx.x * 4 + (threadIdx.x >> 6);
  int lane = threadIdx.x & 63;
  float2 hv = *(const float2*)(h + (size_t)node * D + lane * 2);
  float4 wv = *(const float4*)(Wout + lane * 4);
  float p0 = hv.x * wv.x + hv.y * wv.z;
  float p1 = hv.x * wv.y + hv.y * wv.w;
#pragma unroll
  for (int off = 32; off > 0; off >>= 1) {
    p0 += __shfl_down(p0, off, 64);
    p1 += __shfl_down(p1, off, 64);
  }
  if (lane == 0) {
    out[node * 2 + 0] = p0 + bout[0];
    out[node * 2 + 1] = p1 + bout[1];
  }
}

// ---------------- launch ----------------

extern "C" void kernel_launch(void* const* d_in, const int* in_sizes, int n_in,
                              void* d_out, int out_size, void* d_ws, size_t ws_size,
                              hipStream_t stream) {
  const float* x = (const float*)d_in[0];
  const int* src = (const int*)d_in[1];
  const int* dst = (const int*)d_in[2];
  const float* W1 = (const float*)d_in[3];
  const float* b1 = (const float*)d_in[4];
  const float* W2 = (const float*)d_in[5];
  const float* b2 = (const float*)d_in[6];
  const float* eps = (const float*)d_in[7];
  const float* Wout = (const float*)d_in[8];
  const float* bout = (const float*)d_in[9];
  float* out = (float*)d_out;
  float* n_embed = out + (size_t)2 * N_NODES;  // f32 h lives here between kernels

  char* ws = (char*)d_ws;
  size_t off = 0;
  auto alloc = [&](size_t bytes) -> char* {
    char* p = ws + off;
    off += (bytes + 511) & ~(size_t)511;
    return p;
  };
  short* zh = (short*)alloc(sizeof(short) * (size_t)N_NODES * D);  // 25.6 MB
  short* zl = (short*)alloc(sizeof(short) * (size_t)N_NODES * D);  // 25.6 MB
  int* ssrc = (int*)alloc(sizeof(int) * N_EDGES);                  // 6.4 MB
  int* counts = (int*)alloc(sizeof(int) * N_NODES);
  int* row_ptr = (int*)alloc(sizeof(int) * (N_NODES + 1));
  float* inv_deg = (float*)alloc(sizeof(float) * N_NODES);
  int* bsum = (int*)alloc(sizeof(int) * 128);
  int* boff = (int*)alloc(sizeof(int) * 128);
  int* bucket_cursor = (int*)alloc(sizeof(int) * 128);
  short* WT = (short*)alloc(sizeof(short) * 6 * 2 * 16384);        // 768 KB
  // ebuf (12.8 MB) aliases zh: dead before the first k_agg writes zh.
  int2* ebuf = (int2*)zh;

  // CSR build: count -> scan -> partition -> bucket-local sort
  hipMemsetAsync(counts, 0, sizeof(int) * N_NODES, stream);
  k_count<<<N_EDGES / 256, 256, 0, stream>>>(dst, counts);
  k_scan1<<<N_SCAN_BLOCKS, 256, 0, stream>>>(counts, bsum);
  k_scan2<<<1, 64, 0, stream>>>(bsum, boff, row_ptr, N_SCAN_BLOCKS);
  k_scan3<<<N_SCAN_BLOCKS, 256, 0, stream>>>(counts, boff, row_ptr, inv_deg);
  k_binit<<<1, 128, 0, stream>>>(row_ptr, bucket_cursor);
  k_part<<<N_PART_BLOCKS, 1024, 0, stream>>>(src, dst, bucket_cursor, ebuf);
  k_lsort<<<N_BUCKETS, 1024, 0, stream>>>(ebuf, row_ptr, ssrc);

  // W split/transpose (all 6 matrices)
  k_wprep<<<dim3(64, 6), 256, 0, stream>>>(W1, W2, WT);

  const int gemm_grid = (N_NODES + 127) / 128;  // 782
  // Per layer: agg(h -> planes); gemm1(planes -> planes, in-place); gemm2(planes -> h f32)
  for (int l = 0; l < 3; l++) {
    const float* hin = (l == 0) ? x : n_embed;
    const short* w1h = WT + (size_t)l * 2 * 16384;
    const short* w1l = w1h + 16384;
    const short* w2h = WT + (size_t)(3 + l) * 2 * 16384;
    const short* w2l = w2h + 16384;
    k_agg<<<N_NODES / 4, 256, 0, stream>>>(hin, zh, zl, row_ptr, ssrc, inv_deg, eps, l);
    k_gemm<<<gemm_grid, 256, 0, stream>>>(zh, zl, w1h, w1l, b1 + (size_t)l * D,
                                          (float*)nullptr, zh, zl, N_NODES, 1);
    k_gemm<<<gemm_grid, 256, 0, stream>>>(zh, zl, w2h, w2l, b2 + (size_t)l * D,
                                          n_embed, (short*)nullptr, (short*)nullptr,
                                          N_NODES, 0);
  }
  k_out<<<N_NODES / 4, 256, 0, stream>>>(n_embed, Wout, bout, out);
}